// Round 1
// baseline (1451.819 us; speedup 1.0000x reference)
//
#include <hip/hip_runtime.h>
#include <math.h>

#define E_ 32
#define G_ 16
#define HID_ 1024
#define INTER_ 2048
#define AINTER_ 128
#define CAP_ 160
#define MAXG_ 320
#define SCALE_ 0.05f

typedef unsigned short u16;
typedef unsigned int u32;
typedef short s16x8 __attribute__((ext_vector_type(8)));
typedef float f32x4 __attribute__((ext_vector_type(4)));

__device__ __forceinline__ u16 f2bf(float f) {
  u32 u = __float_as_uint(f);
  return (u16)((u + 0x7FFFu + ((u >> 16) & 1u)) >> 16);
}
__device__ __forceinline__ float bf2f(u16 b) {
  return __uint_as_float(((u32)b) << 16);
}
__device__ __forceinline__ void gload16(void* lds, const void* g) {
  __builtin_amdgcn_global_load_lds((const __attribute__((address_space(1))) u32*)g,
                                   (__attribute__((address_space(3))) u32*)lds, 16, 0, 0);
}

// ---------------- stats + bf16 hi/lo split of x ----------------
__global__ __launch_bounds__(256) void k_stats(const float* __restrict__ x,
    float* __restrict__ stats, u16* __restrict__ xhi, u16* __restrict__ xlo) {
  int t = blockIdx.x, tid = threadIdx.x;
  const float4 v = ((const float4*)(x + (size_t)t * HID_))[tid];
  float f[4] = {v.x, v.y, v.z, v.w};
  unsigned long long ph = 0, pl = 0;
  float s = 0.f, s2 = 0.f, mn = 1e30f, mx = -1e30f; int cnt = 0;
#pragma unroll
  for (int i = 0; i < 4; i++) {
    u16 h = f2bf(f[i]);
    float fh = bf2f(h);
    u16 l = f2bf(f[i] - fh);
    ph |= ((unsigned long long)h) << (16 * i);
    pl |= ((unsigned long long)l) << (16 * i);
    s += f[i]; s2 += f[i] * f[i];
    mn = fminf(mn, f[i]); mx = fmaxf(mx, f[i]);
    cnt += (fabsf(f[i]) < 1e-6f) ? 1 : 0;
  }
  ((unsigned long long*)(xhi + (size_t)t * HID_))[tid] = ph;
  ((unsigned long long*)(xlo + (size_t)t * HID_))[tid] = pl;
#pragma unroll
  for (int d = 32; d; d >>= 1) {
    s += __shfl_xor(s, d); s2 += __shfl_xor(s2, d);
    mn = fminf(mn, __shfl_xor(mn, d)); mx = fmaxf(mx, __shfl_xor(mx, d));
    cnt += __shfl_xor(cnt, d);
  }
  __shared__ float rs[4], rs2[4], rmn[4], rmx[4];
  __shared__ int rc[4];
  int wid = tid >> 6;
  if ((tid & 63) == 0) { rs[wid] = s; rs2[wid] = s2; rmn[wid] = mn; rmx[wid] = mx; rc[wid] = cnt; }
  __syncthreads();
  if (tid == 0) {
    float S = 0.f, S2 = 0.f, MN = 1e30f, MX = -1e30f; int C = 0;
    for (int i = 0; i < 4; i++) { S += rs[i]; S2 += rs2[i]; MN = fminf(MN, rmn[i]); MX = fmaxf(MX, rmx[i]); C += rc[i]; }
    float mean = S * (1.0f / HID_);
    float var = (S2 - HID_ * mean * mean) * (1.0f / (HID_ - 1));
    float* o = stats + (size_t)t * 6;
    o[0] = mean; o[1] = sqrtf(fmaxf(var, 0.f)); o[2] = MN; o[3] = MX;
    o[4] = sqrtf(S2); o[5] = C * (1.0f / HID_);
  }
}

// ---------------- router layer1: fp32 GEMM + exact gelu ----------------
// h[T,512] = gelu([x | stats] @ r1_w^T + b), K=1030
__global__ __launch_bounds__(256) void k_router1(const float* __restrict__ xf,
    const float* __restrict__ stats, const float* __restrict__ w,
    const float* __restrict__ b, float* __restrict__ h) {
  __shared__ float As[32][132];
  __shared__ float Bs[32][68];
  const int K = HID_ + 6;
  int m0 = blockIdx.y * 128, n0 = blockIdx.x * 64;
  int tid = threadIdx.x;
  int tx = tid & 15, ty = tid >> 4;
  float acc[8][4] = {};
  for (int k0 = 0; k0 < K; k0 += 32) {
    __syncthreads();
#pragma unroll
    for (int i = 0; i < 16; i++) {   // A: 128x32
      int flat = i * 256 + tid;
      int m = flat >> 5, k = flat & 31;
      int gk = k0 + k, t = m0 + m;
      float val = 0.f;
      if (gk < HID_) val = xf[(size_t)t * HID_ + gk];
      else if (gk < K) val = stats[(size_t)t * 6 + (gk - HID_)];
      As[k][m] = val;
    }
#pragma unroll
    for (int i = 0; i < 8; i++) {    // B: 64x32
      int flat = i * 256 + tid;
      int n = flat >> 5, k = flat & 31;
      int gk = k0 + k;
      Bs[k][n] = (gk < K) ? w[(size_t)(n0 + n) * K + gk] : 0.f;
    }
    __syncthreads();
#pragma unroll
    for (int k = 0; k < 32; k++) {
      float a[8], bb[4];
#pragma unroll
      for (int j = 0; j < 4; j++) bb[j] = Bs[k][tx * 4 + j];
#pragma unroll
      for (int i = 0; i < 8; i++) a[i] = As[k][ty * 8 + i];
#pragma unroll
      for (int i = 0; i < 8; i++)
#pragma unroll
        for (int j = 0; j < 4; j++) acc[i][j] += a[i] * bb[j];
    }
  }
#pragma unroll
  for (int i = 0; i < 8; i++) {
    int m = m0 + ty * 8 + i;
#pragma unroll
    for (int j = 0; j < 4; j++) {
      int n = n0 + tx * 4 + j;
      float v = acc[i][j] + b[n];
      v = 0.5f * v * (1.0f + erff(v * 0.7071067811865475f));
      h[(size_t)m * 512 + n] = v;
    }
  }
}

// ---------------- router layer2 + softmax + top2 ----------------
__global__ __launch_bounds__(256) void k_router2(const float* __restrict__ h,
    const float* __restrict__ r2w, float* __restrict__ probs,
    int* __restrict__ topi, float* __restrict__ topw) {
  int t = blockIdx.x, tid = threadIdx.x;
  int e = tid >> 3, pp = tid & 7;
  const float* hr = h + (size_t)t * 512;
  const float* wr = r2w + (size_t)e * 512;
  float s = 0.f;
  for (int j = pp * 64; j < pp * 64 + 64; j += 4) {
    float4 a = *(const float4*)(hr + j);
    float4 bb = *(const float4*)(wr + j);
    s += a.x * bb.x + a.y * bb.y + a.z * bb.z + a.w * bb.w;
  }
  s += __shfl_xor(s, 4); s += __shfl_xor(s, 2); s += __shfl_xor(s, 1);
  __shared__ float logits[E_];
  if (pp == 0) logits[e] = s;
  __syncthreads();
  if (tid == 0) {
    float mx = -1e30f;
#pragma unroll
    for (int i = 0; i < E_; i++) mx = fmaxf(mx, logits[i]);
    float sum = 0.f;
    float ex[E_];
#pragma unroll
    for (int i = 0; i < E_; i++) { ex[i] = expf(logits[i] - mx); sum += ex[i]; }
    float inv = 1.f / sum;
    float p1 = -1.f, p2 = -1.f; int i1 = 0, i2 = 1;
#pragma unroll
    for (int i = 0; i < E_; i++) {
      float v = ex[i] * inv;
      probs[(size_t)t * E_ + i] = v;
      if (v > p1) { p2 = p1; i2 = i1; p1 = v; i1 = i; }
      else if (v > p2) { p2 = v; i2 = i; }
    }
    float ws = p1 + p2;
    topi[t * 2] = i1; topi[t * 2 + 1] = i2;
    topw[t * 2] = p1 / ws; topw[t * 2 + 1] = p2 / ws;
  }
}

// ---------------- per-expert capacity selection (exact top-cap by prob) ----------------
__global__ __launch_bounds__(256) void k_capacity(const float* __restrict__ probs,
    const int* __restrict__ topi, const float* __restrict__ topw,
    int* __restrict__ idxbuf, float* __restrict__ wbuf,
    int* __restrict__ tok_nslots, int* __restrict__ tok_slots,
    int* __restrict__ tok_na, int* __restrict__ tok_aslots,
    int* __restrict__ gcnt, int* __restrict__ aglist, float* __restrict__ agw,
    int T, int cap) {
  int e = blockIdx.x, tid = threadIdx.x;
  __shared__ u32 keys[4096];
  __shared__ float wvs[4096];
  __shared__ u32 scnt;
  __shared__ int c1;
  for (int t = tid; t < T; t += 256) {
    int i0 = topi[t * 2], i1 = topi[t * 2 + 1];
    float wv = 0.f; bool routed = false;
    if (i0 == e) { routed = true; wv = topw[t * 2]; }
    else if (i1 == e) { routed = true; wv = topw[t * 2 + 1]; }
    u32 key = 0;
    if (routed) key = __float_as_uint(probs[(size_t)t * E_ + e]);
    keys[t] = key; wvs[t] = wv;
  }
  __syncthreads();
  u32 cur = 0;
  for (int bit = 30; bit >= 0; bit--) {
    u32 cand = cur | (1u << bit);
    if (tid == 0) scnt = 0;
    __syncthreads();
    u32 local = 0;
    for (int t = tid; t < T; t += 256) local += (keys[t] >= cand) ? 1u : 0u;
    atomicAdd(&scnt, local);
    __syncthreads();
    if (scnt >= (u32)cap) cur = cand;
    __syncthreads();
  }
  if (tid == 0) c1 = 0;
  __syncthreads();
  // pass 1: strictly greater than threshold (guaranteed < cap of them)
  for (int t = tid; t < T; t += 256) {
    if (keys[t] > cur) {
      int pos = atomicAdd(&c1, 1);
      float wv = wvs[t];
      idxbuf[e * cap + pos] = t; wbuf[e * cap + pos] = wv;
      int sl = atomicAdd(&tok_nslots[t], 1);
      tok_slots[t * 2 + sl] = e * cap + pos;
      int g = e >> 1;
      int ap = atomicAdd(&gcnt[g], 1);
      aglist[g * MAXG_ + ap] = t; agw[g * MAXG_ + ap] = SCALE_ * wv;
      int na = atomicAdd(&tok_na[t], 1);
      tok_aslots[t * 2 + na] = g * MAXG_ + ap;
    }
  }
  __syncthreads();
  // pass 2: equal-to-threshold fill
  if (cur > 0) {
    for (int t = tid; t < T; t += 256) {
      if (keys[t] == cur) {
        int pos = atomicAdd(&c1, 1);
        if (pos < cap) {
          float wv = wvs[t];
          idxbuf[e * cap + pos] = t; wbuf[e * cap + pos] = wv;
          int sl = atomicAdd(&tok_nslots[t], 1);
          tok_slots[t * 2 + sl] = e * cap + pos;
          int g = e >> 1;
          int ap = atomicAdd(&gcnt[g], 1);
          aglist[g * MAXG_ + ap] = t; agw[g * MAXG_ + ap] = SCALE_ * wv;
          int na = atomicAdd(&tok_na[t], 1);
          tok_aslots[t * 2 + na] = g * MAXG_ + ap;
        }
      }
    }
  }
  __syncthreads();
  int start = c1 < cap ? c1 : cap;
  for (int pos = start + tid; pos < cap; pos += 256) {
    idxbuf[e * cap + pos] = 0; wbuf[e * cap + pos] = 0.f;
  }
}

// ---------------- fused gate/up MFMA GEMM + SiLU (A split hi/lo) ----------------
// per block: 160 rows (gathered tokens) x 64 gate cols + matching 64 up cols, K=1024
__global__ __launch_bounds__(256) void k_gateup(
    const u16* __restrict__ xhi, const u16* __restrict__ xlo,
    const int* __restrict__ list, int listPitch, const int* __restrict__ cnts,
    const float* __restrict__ W, size_t wPitchZ, int upOff,
    u16* __restrict__ out, size_t outPitchZ, int outPitchRow) {
  int z = blockIdx.z;
  int n0 = blockIdx.x * 64;
  int m0 = blockIdx.y * 160;
  int count = cnts ? (cnts[z] - m0) : CAP_;
  if (count <= 0) return;
  if (count > 160) count = 160;
  const int* rl = list + (size_t)z * listPitch + m0;
  const float* Wz = W + (size_t)z * wPitchZ;
  __shared__ u16 AsH[160 * 64];
  __shared__ u16 AsL[160 * 64];
  __shared__ u16 Bs[128 * 64];
  int tid = threadIdx.x, wid = tid >> 6, lane = tid & 63;
  f32x4 accg[10] = {};
  f32x4 accu[10] = {};
  for (int k0 = 0; k0 < HID_; k0 += 64) {
    if (k0) __syncthreads();
#pragma unroll
    for (int i = 0; i < 5; i++) {          // A: 160x64 bf16 (x2 arrays), swizzled source
      int idx16 = i * 256 + tid;
      int r = idx16 >> 3, c = idx16 & 7;
      int sc = c ^ (r & 7);
      int tok = (r < count) ? rl[r] : rl[0];
      size_t so = (size_t)tok * HID_ + k0 + sc * 8;
      int dbase = (i * 256 + wid * 64) * 8;
      gload16(&AsH[dbase], xhi + so);
      gload16(&AsL[dbase], xlo + so);
    }
#pragma unroll
    for (int i = 0; i < 4; i++) {          // B: 128 rows (64 gate + 64 up) x 64, fp32->bf16
      int flat = i * 256 + tid;
      int r = flat >> 3, c = flat & 7;
      const float* src = (r < 64) ? (Wz + (size_t)(n0 + r) * HID_)
                                  : (Wz + (size_t)(upOff + n0 + (r - 64)) * HID_);
      src += k0 + c * 8;
      float4 f0 = ((const float4*)src)[0];
      float4 f1 = ((const float4*)src)[1];
      s16x8 pk;
      pk[0] = (short)f2bf(f0.x); pk[1] = (short)f2bf(f0.y);
      pk[2] = (short)f2bf(f0.z); pk[3] = (short)f2bf(f0.w);
      pk[4] = (short)f2bf(f1.x); pk[5] = (short)f2bf(f1.y);
      pk[6] = (short)f2bf(f1.z); pk[7] = (short)f2bf(f1.w);
      int d16 = r * 8 + (c ^ (r & 7));
      *((s16x8*)&Bs[d16 * 8]) = pk;
    }
    __syncthreads();
#pragma unroll
    for (int ks = 0; ks < 2; ks++) {
      int cb = ks * 4 + (lane >> 4);
      int rg = wid * 16 + (lane & 15);
      int ru = 64 + rg;
      s16x8 bg = *((const s16x8*)&Bs[(rg * 8 + (cb ^ (rg & 7))) * 8]);
      s16x8 bu = *((const s16x8*)&Bs[(ru * 8 + (cb ^ (ru & 7))) * 8]);
#pragma unroll
      for (int mf = 0; mf < 10; mf++) {
        int rA = mf * 16 + (lane & 15);
        int a16 = (rA * 8 + (cb ^ (rA & 7))) * 8;
        s16x8 ah = *((const s16x8*)&AsH[a16]);
        s16x8 al = *((const s16x8*)&AsL[a16]);
        accg[mf] = __builtin_amdgcn_mfma_f32_16x16x32_bf16(ah, bg, accg[mf], 0, 0, 0);
        accg[mf] = __builtin_amdgcn_mfma_f32_16x16x32_bf16(al, bg, accg[mf], 0, 0, 0);
        accu[mf] = __builtin_amdgcn_mfma_f32_16x16x32_bf16(ah, bu, accu[mf], 0, 0, 0);
        accu[mf] = __builtin_amdgcn_mfma_f32_16x16x32_bf16(al, bu, accu[mf], 0, 0, 0);
      }
    }
  }
  int colc = lane & 15, rq = lane >> 4;
  u16* ob = out + (size_t)z * outPitchZ + n0 + wid * 16 + colc;
#pragma unroll
  for (int mf = 0; mf < 10; mf++) {
#pragma unroll
    for (int i = 0; i < 4; i++) {
      int m = mf * 16 + rq * 4 + i;
      if (m < count) {
        float g = accg[mf][i], u = accu[mf][i];
        float hv = g / (1.f + __expf(-g)) * u;
        ob[(size_t)(m0 + m) * outPitchRow] = f2bf(hv);
      }
    }
  }
}

// ---------------- down-proj MFMA GEMM ----------------
__global__ __launch_bounds__(256) void k_down(
    const u16* __restrict__ H, size_t hPitchZ, int K,
    const int* __restrict__ cnts,
    const float* __restrict__ W, size_t wPitchZ,
    float* __restrict__ out, size_t outPitchZ) {
  int z = blockIdx.z;
  int n0 = blockIdx.x * 64;
  int m0 = blockIdx.y * 160;
  int count = cnts ? (cnts[z] - m0) : CAP_;
  if (count <= 0) return;
  if (count > 160) count = 160;
  const u16* Hz = H + (size_t)z * hPitchZ;
  const float* Wz = W + (size_t)z * wPitchZ;
  __shared__ u16 As[160 * 64];
  __shared__ u16 Bs[64 * 64];
  int tid = threadIdx.x, wid = tid >> 6, lane = tid & 63;
  f32x4 acc[10] = {};
  for (int k0 = 0; k0 < K; k0 += 64) {
    if (k0) __syncthreads();
#pragma unroll
    for (int i = 0; i < 5; i++) {
      int idx16 = i * 256 + tid;
      int r = idx16 >> 3, c = idx16 & 7;
      int sc = c ^ (r & 7);
      int rr = (r < count) ? r : 0;
      gload16(&As[(i * 256 + wid * 64) * 8], Hz + (size_t)(m0 + rr) * K + k0 + sc * 8);
    }
#pragma unroll
    for (int i = 0; i < 2; i++) {
      int flat = i * 256 + tid;
      int r = flat >> 3, c = flat & 7;
      const float* src = Wz + (size_t)(n0 + r) * K + k0 + c * 8;
      float4 f0 = ((const float4*)src)[0];
      float4 f1 = ((const float4*)src)[1];
      s16x8 pk;
      pk[0] = (short)f2bf(f0.x); pk[1] = (short)f2bf(f0.y);
      pk[2] = (short)f2bf(f0.z); pk[3] = (short)f2bf(f0.w);
      pk[4] = (short)f2bf(f1.x); pk[5] = (short)f2bf(f1.y);
      pk[6] = (short)f2bf(f1.z); pk[7] = (short)f2bf(f1.w);
      int d16 = r * 8 + (c ^ (r & 7));
      *((s16x8*)&Bs[d16 * 8]) = pk;
    }
    __syncthreads();
#pragma unroll
    for (int ks = 0; ks < 2; ks++) {
      int cb = ks * 4 + (lane >> 4);
      int rb = wid * 16 + (lane & 15);
      s16x8 b = *((const s16x8*)&Bs[(rb * 8 + (cb ^ (rb & 7))) * 8]);
#pragma unroll
      for (int mf = 0; mf < 10; mf++) {
        int rA = mf * 16 + (lane & 15);
        s16x8 a = *((const s16x8*)&As[(rA * 8 + (cb ^ (rA & 7))) * 8]);
        acc[mf] = __builtin_amdgcn_mfma_f32_16x16x32_bf16(a, b, acc[mf], 0, 0, 0);
      }
    }
  }
  int colc = lane & 15, rq = lane >> 4;
  float* ob = out + (size_t)z * outPitchZ + n0 + wid * 16 + colc;
#pragma unroll
  for (int mf = 0; mf < 10; mf++) {
#pragma unroll
    for (int i = 0; i < 4; i++) {
      int m = mf * 16 + rq * 4 + i;
      if (m < count) ob[(size_t)(m0 + m) * HID_] = acc[mf][i];
    }
  }
}

// ---------------- combine: out[t] = sum w*ye + sum gw*ay ----------------
__global__ __launch_bounds__(256) void k_combine(
    const float* __restrict__ ye, const float* __restrict__ ay,
    const int* __restrict__ tok_nslots, const int* __restrict__ tok_slots,
    const float* __restrict__ wbuf,
    const int* __restrict__ tok_na, const int* __restrict__ tok_aslots,
    const float* __restrict__ agw, float* __restrict__ out) {
  int t = blockIdx.x, tid = threadIdx.x;
  float ax = 0.f, ayv = 0.f, az = 0.f, aw = 0.f;
  int ns = tok_nslots[t];
  for (int s = 0; s < ns; s++) {
    int slot = tok_slots[t * 2 + s];
    float wv = wbuf[slot];
    float4 v = ((const float4*)(ye + (size_t)slot * HID_))[tid];
    ax += wv * v.x; ayv += wv * v.y; az += wv * v.z; aw += wv * v.w;
  }
  int na = tok_na[t];
  for (int s = 0; s < na; s++) {
    int as = tok_aslots[t * 2 + s];
    float gv = agw[as];
    float4 v = ((const float4*)(ay + (size_t)as * HID_))[tid];
    ax += gv * v.x; ayv += gv * v.y; az += gv * v.z; aw += gv * v.w;
  }
  float4 r; r.x = ax; r.y = ayv; r.z = az; r.w = aw;
  ((float4*)(out + (size_t)t * HID_))[tid] = r;
}

extern "C" void kernel_launch(void* const* d_in, const int* in_sizes, int n_in,
                              void* d_out, int out_size, void* d_ws, size_t ws_size,
                              hipStream_t stream) {
  const float* x   = (const float*)d_in[0];
  const float* r1w = (const float*)d_in[1];
  const float* r1b = (const float*)d_in[2];
  const float* r2w = (const float*)d_in[3];
  const float* wup = (const float*)d_in[4];
  const float* wdn = (const float*)d_in[5];
  const float* aup = (const float*)d_in[6];
  const float* adn = (const float*)d_in[7];
  float* out = (float*)d_out;
  int T = in_sizes[0] / HID_;   // 4096

  char* p = (char*)d_ws;
  auto alloc = [&](size_t bytes) { char* r = p; p += (bytes + 255) & ~(size_t)255; return r; };
  u16*   xhi        = (u16*)  alloc((size_t)T * HID_ * 2);
  u16*   xlo        = (u16*)  alloc((size_t)T * HID_ * 2);
  float* stats      = (float*)alloc((size_t)T * 6 * 4);
  float* h          = (float*)alloc((size_t)T * 512 * 4);
  float* probs      = (float*)alloc((size_t)T * E_ * 4);
  int*   topi       = (int*)  alloc((size_t)T * 2 * 4);
  float* topw       = (float*)alloc((size_t)T * 2 * 4);
  int*   idxbuf     = (int*)  alloc((size_t)E_ * CAP_ * 4);
  float* wbuf       = (float*)alloc((size_t)E_ * CAP_ * 4);
  int*   zerobase   = (int*)  alloc((size_t)(2 * T + G_) * 4);
  int*   tok_nslots = zerobase;
  int*   tok_na     = zerobase + T;
  int*   gcnt       = zerobase + 2 * T;
  int*   tok_slots  = (int*)  alloc((size_t)T * 2 * 4);
  int*   tok_aslots = (int*)  alloc((size_t)T * 2 * 4);
  int*   aglist     = (int*)  alloc((size_t)G_ * MAXG_ * 4);
  float* agw        = (float*)alloc((size_t)G_ * MAXG_ * 4);
  u16*   hact_e     = (u16*)  alloc((size_t)E_ * CAP_ * INTER_ * 2);
  float* ye         = (float*)alloc((size_t)E_ * CAP_ * HID_ * 4);
  u16*   hact_a     = (u16*)  alloc((size_t)G_ * MAXG_ * AINTER_ * 2);
  float* ay         = (float*)alloc((size_t)G_ * MAXG_ * HID_ * 4);
  (void)ws_size; (void)n_in; (void)out_size;

  hipMemsetAsync(zerobase, 0, (size_t)(2 * T + G_) * 4, stream);
  k_stats<<<T, 256, 0, stream>>>(x, stats, xhi, xlo);
  k_router1<<<dim3(512 / 64, T / 128), 256, 0, stream>>>(x, stats, r1w, r1b, h);
  k_router2<<<T, 256, 0, stream>>>(h, r2w, probs, topi, topw);
  k_capacity<<<E_, 256, 0, stream>>>(probs, topi, topw, idxbuf, wbuf,
      tok_nslots, tok_slots, tok_na, tok_aslots, gcnt, aglist, agw, T, CAP_);
  // experts: gate/up (N half = 2048) then down (K=2048)
  k_gateup<<<dim3(INTER_ / 64, 1, E_), 256, 0, stream>>>(xhi, xlo, idxbuf, CAP_, (const int*)nullptr,
      wup, (size_t)2 * INTER_ * HID_, INTER_, hact_e, (size_t)CAP_ * INTER_, INTER_);
  // adjugate: gate/up (N half = 128), up to 320 tokens per group (2 M-tiles)
  k_gateup<<<dim3(AINTER_ / 64, 2, G_), 256, 0, stream>>>(xhi, xlo, aglist, MAXG_, gcnt,
      aup, (size_t)2 * AINTER_ * HID_, AINTER_, hact_a, (size_t)MAXG_ * AINTER_, AINTER_);
  k_down<<<dim3(HID_ / 64, 1, E_), 256, 0, stream>>>(hact_e, (size_t)CAP_ * INTER_, INTER_, (const int*)nullptr,
      wdn, (size_t)HID_ * INTER_, ye, (size_t)CAP_ * HID_);
  k_down<<<dim3(HID_ / 64, 2, G_), 256, 0, stream>>>(hact_a, (size_t)MAXG_ * AINTER_, AINTER_, gcnt,
      adn, (size_t)HID_ * AINTER_, ay, (size_t)MAXG_ * HID_);
  k_combine<<<T, 256, 0, stream>>>(ye, ay, tok_nslots, tok_slots, wbuf,
      tok_na, tok_aslots, agw, out);
}